// Round 10
// baseline (338.576 us; speedup 1.0000x reference)
//
#include <hip/hip_runtime.h>

// x is (B=32, C=256, H=64, W=64) fp32.
#define NB 32
#define NC 256
#define NH 64
#define NW 64
#define HW (NH * NW)          // 4096

// Native 4-float vector for __builtin_nontemporal_store.
typedef float nfloat4 __attribute__((ext_vector_type(4)));

// Workspace layout (float offsets).
static constexpr size_t OFF_HSUM = 0;                           // (unused now)
static constexpr size_t OFF_WSUM = OFF_HSUM + (size_t)NB*NC*NH; // (unused now)
static constexpr size_t OFF_CSUM = OFF_WSUM + (size_t)NB*NC*NW; // [B][C]
static constexpr size_t OFF_VSP  = OFF_CSUM + (size_t)NB*NC;    // (unused now)
static constexpr size_t OFF_VH   = OFF_VSP  + (size_t)NB*NC;    // (unused now)
static constexpr size_t OFF_VW   = OFF_VH   + (size_t)NB*NH;    // (unused now)
static constexpr size_t OFF_SH   = OFF_VW   + (size_t)NB*NW;    // [B][C][W]
static constexpr size_t OFF_SW   = OFF_SH   + (size_t)NB*NC*NW; // [B][H][C]
static constexpr size_t OFF_PART = OFF_SW   + (size_t)NB*NH*NC; // [B][32][HW] s_sp partials
static constexpr size_t OFF_PSP  = OFF_PART + (size_t)NB*32*HW; // [B][HW]
static constexpr size_t OFF_PSH  = OFF_PSP  + (size_t)NB*HW;    // [B][C][W]
static constexpr size_t OFF_PSW  = OFF_PSH  + (size_t)NB*NC*NW; // [B][H][C]
static constexpr size_t OFF_PARTH= OFF_PSW  + (size_t)NB*NH*NC; // [B][32][64] row partials
static constexpr size_t OFF_PARTW= OFF_PARTH+ (size_t)NB*32*64; // [B][32][64] col partials

// ---------------------------------------------------------------------------
// K1': stats pass. 1024 blocks x 8 planes of one b (strip = blk&31).
// Key insight: hsum/wsum are only consumed summed over c, so row/col sums
// accumulate in REGISTERS across the 8 planes and reduce ONCE per block
// (~6-8x less LDS-unit time than per-plane trees). csum (needed per plane)
// uses cheap per-plane scalar partials + one 8-value wave-shfl reduce.
// Outputs: PARTH[b][strip][h], PARTW[b][strip][w], csum[b][c] (exact).
// ---------------------------------------------------------------------------
__global__ __launch_bounds__(256) void k_stats2(const float* __restrict__ x,
                                                float* __restrict__ ws) {
    const int blk = blockIdx.x;
    const int t   = threadIdx.x;
    const int b = blk >> 5, strip = blk & 31;
    const int h0 = t >> 4, w4 = t & 15;
    const int bc0 = blk * 8;

    float ra0 = 0.f, ra1 = 0.f, ra2 = 0.f, ra3 = 0.f;   // row accs (h0+16k)
    float4 colacc = make_float4(0.f, 0.f, 0.f, 0.f);     // cols 4*w4..+3
    float ps[8];                                          // per-plane totals

    const float4* base = reinterpret_cast<const float4*>(x) + ((size_t)bc0 << 10);
    #pragma unroll
    for (int p = 0; p < 8; ++p) {
        const float4* plane = base + ((size_t)p << 10);
        const float4 v0 = plane[t];
        const float4 v1 = plane[t + 256];
        const float4 v2 = plane[t + 512];
        const float4 v3 = plane[t + 768];
        const float hp0 = v0.x + v0.y + v0.z + v0.w;
        const float hp1 = v1.x + v1.y + v1.z + v1.w;
        const float hp2 = v2.x + v2.y + v2.z + v2.w;
        const float hp3 = v3.x + v3.y + v3.z + v3.w;
        ps[p] = hp0 + hp1 + hp2 + hp3;
        ra0 += hp0; ra1 += hp1; ra2 += hp2; ra3 += hp3;
        colacc.x += v0.x + v1.x + v2.x + v3.x;
        colacc.y += v0.y + v1.y + v2.y + v3.y;
        colacc.z += v0.z + v1.z + v2.z + v3.z;
        colacc.w += v0.w + v1.w + v2.w + v3.w;
    }

    // Row sums: one shfl reduce over the 16 lanes sharing h (once per block).
    #pragma unroll
    for (int d = 1; d < 16; d <<= 1) {
        ra0 += __shfl_xor(ra0, d);
        ra1 += __shfl_xor(ra1, d);
        ra2 += __shfl_xor(ra2, d);
        ra3 += __shfl_xor(ra3, d);
    }
    if (w4 == 0) {
        float* ph = ws + OFF_PARTH + ((size_t)b * 32 + strip) * 64;
        ph[h0]      = ra0;
        ph[h0 + 16] = ra1;
        ph[h0 + 32] = ra2;
        ph[h0 + 48] = ra3;
    }

    // Col sums: one float4 LDS tree (once per block).
    __shared__ float4 red4[256];
    red4[t] = colacc;
    __syncthreads();
    for (int s2 = 128; s2 >= 16; s2 >>= 1) {
        if (t < s2) {
            red4[t].x += red4[t + s2].x;
            red4[t].y += red4[t + s2].y;
            red4[t].z += red4[t + s2].z;
            red4[t].w += red4[t + s2].w;
        }
        __syncthreads();
    }
    if (t < 16)
        reinterpret_cast<float4*>(ws + OFF_PARTW + ((size_t)b * 32 + strip) * 64)[t] = red4[t];

    // csum: 8 values wave-reduced, then cross-wave via tiny LDS.
    #pragma unroll
    for (int p = 0; p < 8; ++p) {
        #pragma unroll
        for (int d = 1; d < 64; d <<= 1) ps[p] += __shfl_xor(ps[p], d);
    }
    __shared__ float wsum8[4][8];
    const int lane = t & 63, wid = t >> 6;
    if (lane == 0) {
        #pragma unroll
        for (int p = 0; p < 8; ++p) wsum8[wid][p] = ps[p];
    }
    __syncthreads();
    if (t < 8)
        ws[OFF_CSUM + bc0 + t] = wsum8[0][t] + wsum8[1][t] + wsum8[2][t] + wsum8[3][t];
}

// ---------------------------------------------------------------------------
// K2+K3 fused: 1024 blocks. Prologue (redundant per block, ~4KB partial reads
// + L3-resident weights): finish means, compute v_sp/v_h/v_w into LDS.
// Body: round-9-verified scores pass (s_h, s_w, s_sp partials).
// ---------------------------------------------------------------------------
__global__ __launch_bounds__(256) void k_scores2(const float* __restrict__ x,
                                                 const float* __restrict__ wl1,
                                                 const float* __restrict__ wl2,
                                                 const float* __restrict__ wr1,
                                                 const float* __restrict__ wr2,
                                                 float* __restrict__ ws) {
    const int t   = threadIdx.x;
    const int blk = blockIdx.x;
    const int b   = blk >> 5;
    const int h0  = t >> 4, w4 = t & 15;

    __shared__ float xbc[256], xbh[64], xbw[64], x2sp[128], th_s[32], tw_s[32];
    __shared__ float red[256];
    __shared__ float vh_s[64], vw_s[64], vsp_s[256];
    __shared__ float4 red4[256];

    // ---- prologue: means ----
    xbc[t] = ws[OFF_CSUM + (size_t)b * NC + t] * (1.0f / 4096.0f);
    if (t < 64) {
        float s = 0.f;
        const float* ph = ws + OFF_PARTH + (size_t)b * 32 * 64 + t;
        #pragma unroll 8
        for (int s2 = 0; s2 < 32; ++s2) s += ph[s2 * 64];
        xbh[t] = s * (1.0f / 16384.0f);
    } else if (t < 128) {
        const int w = t - 64;
        float s = 0.f;
        const float* pw = ws + OFF_PARTW + (size_t)b * 32 * 64 + w;
        #pragma unroll 8
        for (int s2 = 0; s2 < 32; ++s2) s += pw[s2 * 64];
        xbw[w] = s * (1.0f / 16384.0f);
    }
    __syncthreads();

    // ---- prologue: matvecs (round-9 K2 structure) ----
    if (t < 128) {
        float a = 0.f;
        for (int c = 0; c < 256; ++c) a += wl1[t * 256 + c] * xbc[c];
        x2sp[t] = a;
    } else if (t < 160) {
        const int m = t - 128;
        float a = 0.f;
        for (int h = 0; h < 64; ++h) a += wr1[m * 64 + h] * xbh[h];
        th_s[m] = a;
    } else if (t < 192) {
        const int m = t - 160;
        float a = 0.f;
        for (int h = 0; h < 64; ++h) a += wr1[m * 64 + h] * xbw[h];
        tw_s[m] = a;
    }
    __syncthreads();

    {
        float a = 0.f;
        for (int m = 0; m < 128; ++m) a += x2sp[m] * wl2[m * 256 + t];
        vsp_s[t] = a;
    }
    if (t < 64) {
        float a = 0.f;
        for (int m = 0; m < 32; ++m) a += th_s[m] * wr2[m * 64 + t];
        vh_s[t] = a;
    } else if (t < 128) {
        const int w = t - 64;
        float a = 0.f;
        for (int m = 0; m < 32; ++m) a += tw_s[m] * wr2[m * 64 + w];
        vw_s[w] = a;
    }
    __syncthreads();

    // ---- body: scores (round-9 verified) ----
    float4 acc0 = make_float4(0.f,0.f,0.f,0.f);
    float4 acc1 = make_float4(0.f,0.f,0.f,0.f);
    float4 acc2 = make_float4(0.f,0.f,0.f,0.f);
    float4 acc3 = make_float4(0.f,0.f,0.f,0.f);

    for (int p = 0; p < 8; ++p) {
        const int bc = blk * 8 + p;
        const int c  = bc & 255;
        const float4* plane = reinterpret_cast<const float4*>(x) + ((size_t)bc << 10);
        const float4 v0 = plane[t];
        const float4 v1 = plane[t + 256];
        const float4 v2 = plane[t + 512];
        const float4 v3 = plane[t + 768];

        const float4 vwv = reinterpret_cast<const float4*>(vw_s)[w4];
        float hp0 = vwv.x*v0.x + vwv.y*v0.y + vwv.z*v0.z + vwv.w*v0.w;
        float hp1 = vwv.x*v1.x + vwv.y*v1.y + vwv.z*v1.z + vwv.w*v1.w;
        float hp2 = vwv.x*v2.x + vwv.y*v2.y + vwv.z*v2.z + vwv.w*v2.w;
        float hp3 = vwv.x*v3.x + vwv.y*v3.y + vwv.z*v3.z + vwv.w*v3.w;
        #pragma unroll
        for (int d = 1; d < 16; d <<= 1) {
            hp0 += __shfl_xor(hp0, d);
            hp1 += __shfl_xor(hp1, d);
            hp2 += __shfl_xor(hp2, d);
            hp3 += __shfl_xor(hp3, d);
        }
        if (w4 == 0) {
            float* dst = ws + OFF_SW + (size_t)b * NH * NC + c;
            dst[(size_t)(h0)      * NC] = hp0;
            dst[(size_t)(h0 + 16) * NC] = hp1;
            dst[(size_t)(h0 + 32) * NC] = hp2;
            dst[(size_t)(h0 + 48) * NC] = hp3;
        }

        const float a0 = vh_s[h0], a1 = vh_s[h0+16], a2 = vh_s[h0+32], a3 = vh_s[h0+48];
        float4 wp;
        wp.x = a0*v0.x + a1*v1.x + a2*v2.x + a3*v3.x;
        wp.y = a0*v0.y + a1*v1.y + a2*v2.y + a3*v3.y;
        wp.z = a0*v0.z + a1*v1.z + a2*v2.z + a3*v3.z;
        wp.w = a0*v0.w + a1*v1.w + a2*v2.w + a3*v3.w;
        red4[t] = wp;
        __syncthreads();
        for (int s2 = 128; s2 >= 16; s2 >>= 1) {
            if (t < s2) {
                red4[t].x += red4[t + s2].x;
                red4[t].y += red4[t + s2].y;
                red4[t].z += red4[t + s2].z;
                red4[t].w += red4[t + s2].w;
            }
            __syncthreads();
        }
        if (t < 16)
            reinterpret_cast<float4*>(ws + OFF_SH + (size_t)bc * NW)[t] = red4[t];
        __syncthreads();

        const float vc = vsp_s[c];
        acc0.x += vc*v0.x; acc0.y += vc*v0.y; acc0.z += vc*v0.z; acc0.w += vc*v0.w;
        acc1.x += vc*v1.x; acc1.y += vc*v1.y; acc1.z += vc*v1.z; acc1.w += vc*v1.w;
        acc2.x += vc*v2.x; acc2.y += vc*v2.y; acc2.z += vc*v2.z; acc2.w += vc*v2.w;
        acc3.x += vc*v3.x; acc3.y += vc*v3.y; acc3.z += vc*v3.z; acc3.w += vc*v3.w;
    }

    float4* pf4 = reinterpret_cast<float4*>(ws + OFF_PART) +
                  ((size_t)b * 32 + (blk & 31)) * 1024;
    pf4[t]       = acc0;
    pf4[t + 256] = acc1;
    pf4[t + 512] = acc2;
    pf4[t + 768] = acc3;
}

// ---------------------------------------------------------------------------
// K4: softmax + sigmoid per (branch, b). 96 blocks. (round-9 verified)
// ---------------------------------------------------------------------------
__global__ __launch_bounds__(256) void k_softmax(float* __restrict__ ws) {
    const int blk = blockIdx.x, t = threadIdx.x;
    const int kind = blk >> 5, b = blk & 31;
    __shared__ float red[256];
    __shared__ float4 ssp4[1024];

    if (kind == 0) {
        const float4* part = reinterpret_cast<const float4*>(ws + OFF_PART) +
                             (size_t)b * 32 * 1024;
        #pragma unroll
        for (int j = 0; j < 4; ++j) {
            const int n4 = j * 256 + t;
            float4 a = make_float4(0.f,0.f,0.f,0.f);
            for (int s = 0; s < 32; ++s) {
                const float4 v = part[(size_t)s * 1024 + n4];
                a.x += v.x; a.y += v.y; a.z += v.z; a.w += v.w;
            }
            ssp4[n4] = a;
        }
        __syncthreads();

        float mx = -3.4e38f;
        #pragma unroll
        for (int j = 0; j < 4; ++j) {
            const float4 v = ssp4[j * 256 + t];
            mx = fmaxf(mx, fmaxf(fmaxf(v.x, v.y), fmaxf(v.z, v.w)));
        }
        red[t] = mx;
        __syncthreads();
        for (int s = 128; s > 0; s >>= 1) {
            if (t < s) red[t] = fmaxf(red[t], red[t + s]);
            __syncthreads();
        }
        mx = red[0];
        __syncthreads();

        float sm = 0.f;
        #pragma unroll
        for (int j = 0; j < 4; ++j) {
            const float4 v = ssp4[j * 256 + t];
            sm += expf(v.x - mx) + expf(v.y - mx) + expf(v.z - mx) + expf(v.w - mx);
        }
        red[t] = sm;
        __syncthreads();
        for (int s = 128; s > 0; s >>= 1) {
            if (t < s) red[t] += red[t + s];
            __syncthreads();
        }
        const float inv = 1.0f / red[0];
        float4* dst = reinterpret_cast<float4*>(ws + OFF_PSP + (size_t)b * HW);
        #pragma unroll
        for (int j = 0; j < 4; ++j) {
            const float4 v = ssp4[j * 256 + t];
            float4 o;
            o.x = 1.0f / (1.0f + expf(-(expf(v.x - mx) * inv)));
            o.y = 1.0f / (1.0f + expf(-(expf(v.y - mx) * inv)));
            o.z = 1.0f / (1.0f + expf(-(expf(v.z - mx) * inv)));
            o.w = 1.0f / (1.0f + expf(-(expf(v.w - mx) * inv)));
            dst[j * 256 + t] = o;
        }
        return;
    }

    const float* src;
    float* dst;
    const int N = NC * NW;
    if (kind == 1) { src = ws + OFF_SH + (size_t)b * NC * NW; dst = ws + OFF_PSH + (size_t)b * NC * NW; }
    else           { src = ws + OFF_SW + (size_t)b * NH * NC; dst = ws + OFF_PSW + (size_t)b * NH * NC; }

    float mx = -3.4e38f;
    for (int i = t; i < N; i += 256) mx = fmaxf(mx, src[i]);
    red[t] = mx;
    __syncthreads();
    for (int s = 128; s > 0; s >>= 1) {
        if (t < s) red[t] = fmaxf(red[t], red[t + s]);
        __syncthreads();
    }
    mx = red[0];
    __syncthreads();

    float sm = 0.f;
    for (int i = t; i < N; i += 256) sm += expf(src[i] - mx);
    red[t] = sm;
    __syncthreads();
    for (int s = 128; s > 0; s >>= 1) {
        if (t < s) red[t] += red[t + s];
        __syncthreads();
    }
    const float inv = 1.0f / red[0];
    for (int i = t; i < N; i += 256) {
        const float pr = expf(src[i] - mx) * inv;
        dst[i] = 1.0f / (1.0f + expf(-pr));
    }
}

// ---------------------------------------------------------------------------
// K5: out = x * (p_sp + p_h + p_w). (round-9 verified, NT stores)
// ---------------------------------------------------------------------------
__global__ __launch_bounds__(256) void k_final(const float* __restrict__ x,
                                               const float* __restrict__ ws,
                                               float* __restrict__ out) {
    const float* psp = ws + OFF_PSP;
    const float* psh = ws + OFF_PSH;
    const float* psw = ws + OFF_PSW;
    nfloat4* out4 = reinterpret_cast<nfloat4*>(out);
    size_t i4 = (size_t)blockIdx.x * 256 + threadIdx.x;
    #pragma unroll 4
    for (int it = 0; it < 16; ++it, i4 += (size_t)2048 * 256) {
        const int w4 = (int)(i4 & 15);
        const int h  = (int)((i4 >> 4) & 63);
        const int c  = (int)((i4 >> 10) & 255);
        const int b  = (int)(i4 >> 18);
        const float4 xv = reinterpret_cast<const float4*>(x)[i4];
        const float4 sp = reinterpret_cast<const float4*>(psp)[((size_t)b << 10) + (h << 4) + w4];
        const float4 sh = reinterpret_cast<const float4*>(psh)[(((size_t)b << 8) + c) * 16 + w4];
        const float  sw = psw[((size_t)b << 14) + (h << 8) + c];
        nfloat4 o;
        o.x = xv.x * (sp.x + sh.x + sw);
        o.y = xv.y * (sp.y + sh.y + sw);
        o.z = xv.z * (sp.z + sh.z + sw);
        o.w = xv.w * (sp.w + sh.w + sw);
        __builtin_nontemporal_store(o, &out4[i4]);
    }
}

extern "C" void kernel_launch(void* const* d_in, const int* in_sizes, int n_in,
                              void* d_out, int out_size, void* d_ws, size_t ws_size,
                              hipStream_t stream) {
    const float* x   = (const float*)d_in[0];
    const float* wl1 = (const float*)d_in[1];
    const float* wl2 = (const float*)d_in[2];
    const float* wr1 = (const float*)d_in[3];
    const float* wr2 = (const float*)d_in[4];
    float* out = (float*)d_out;
    float* ws  = (float*)d_ws;

    k_stats2 <<<1024, 256, 0, stream>>>(x, ws);
    k_scores2<<<1024, 256, 0, stream>>>(x, wl1, wl2, wr1, wr2, ws);
    k_softmax<<<3 * NB, 256, 0, stream>>>(ws);
    k_final  <<<2048, 256, 0, stream>>>(x, ws, out);
}